// Round 14
// baseline (771.991 us; speedup 1.0000x reference)
//
#include <hip/hip_runtime.h>

#define N_NODES 100000
#define E_EDGES 1000000
#define R_REL   3
#define NBATCH  6250          // N_NODES / 16
#define NBLK    391           // ceil(N_NODES / 256)
#define CNT_BLKS  11721       // 3907 * 3
#define PROJ_BLKS 391
#define A_BLKS    3125        // 800000 / 256
#define FILL_BLKS 3907
#define PS_BLKS   3125        // pull+sem blocks (32 nodes each)
#define REDN      3125        // redpart partials per relation

using bf16x8 = __attribute__((ext_vector_type(8))) short;
using f32x4  = __attribute__((ext_vector_type(4))) float;
using u32x2  = __attribute__((ext_vector_type(2))) unsigned int;

__device__ __forceinline__ float lrelu(float x) { return fmaxf(x, 0.2f * x); }

__device__ __forceinline__ short f2bf(float f) {   // RNE f32->bf16
    unsigned u = __builtin_bit_cast(unsigned, f);
    u += 0x7FFFu + ((u >> 16) & 1u);
    return (short)(u >> 16);
}
__device__ __forceinline__ float bf_lo(unsigned u) {
    return __builtin_bit_cast(float, u << 16);
}
__device__ __forceinline__ float bf_hi(unsigned u) {
    return __builtin_bit_cast(float, u & 0xFFFF0000u);
}
__device__ __forceinline__ float bf2f(unsigned short u) {
    return __builtin_bit_cast(float, ((unsigned)u) << 16);
}

// ---------------------------------------------------------------------------
// Bake bf16 B-fragments for 16x16x32 MFMA (kw, pw full 128x128; lin 4x128).
// ---------------------------------------------------------------------------
__global__ __launch_bounds__(256) void prep_kernel(
    const float* __restrict__ kw, const float* __restrict__ pw,
    const float* __restrict__ lw,
    short* __restrict__ kwB, short* __restrict__ pwB, short* __restrict__ linB)
{
    int idx = blockIdx.x * 256 + threadIdx.x;
    int which, rem;
    if      (idx < 16384) { which = 0; rem = idx; }
    else if (idx < 32768) { which = 1; rem = idx - 16384; }
    else if (idx < 34816) { which = 2; rem = idx - 32768; }
    else return;
    int e = rem & 7, lane = (rem >> 3) & 63, t = rem >> 9;
    int tj = (which == 2) ? 0 : (t >> 2);
    int tk = (which == 2) ? t : (t & 3);
    int j = tj * 16 + (lane & 15);
    int k = tk * 32 + (lane >> 4) * 8 + e;
    const float* src = (which == 0) ? kw : (which == 1) ? pw : lw;
    float v = (which == 2 && j >= 4) ? 0.f : src[j * 128 + k];
    short* dst = (which == 0) ? kwB : (which == 1) ? pwB : linB;
    dst[rem] = f2bf(v);
}

// ---------------------------------------------------------------------------
// proj body (MFMA, full unroll — proven).
// ---------------------------------------------------------------------------
__device__ __forceinline__ void proj_body(
    int bx, const float* __restrict__ x, const short* __restrict__ pwB,
    const float* __restrict__ pb, unsigned short* __restrict__ h_bf)
{
    int wave = threadIdx.x >> 6, lane = threadIdx.x & 63;
    int row16 = lane & 15, kq = lane >> 4;
    for (int b = bx * 4 + wave; b < NBATCH; b += PROJ_BLKS * 4) {
        int nbase = b * 16;
        bf16x8 A[4];
        #pragma unroll
        for (int tk = 0; tk < 4; ++tk) {
            const float* px = x + (size_t)(nbase + row16) * 128 + tk * 32 + kq * 8;
            f32x4 lo = *(const f32x4*)px;
            f32x4 hi = *(const f32x4*)(px + 4);
            bf16x8 a;
            a[0] = f2bf(lo[0]); a[1] = f2bf(lo[1]); a[2] = f2bf(lo[2]); a[3] = f2bf(lo[3]);
            a[4] = f2bf(hi[0]); a[5] = f2bf(hi[1]); a[6] = f2bf(hi[2]); a[7] = f2bf(hi[3]);
            A[tk] = a;
        }
        #pragma unroll
        for (int tj = 0; tj < 8; ++tj) {
            f32x4 c = {0.f, 0.f, 0.f, 0.f};
            #pragma unroll
            for (int tk = 0; tk < 4; ++tk) {
                bf16x8 B = *(const bf16x8*)(pwB + ((size_t)(tj * 4 + tk) * 64 + lane) * 8);
                c = __builtin_amdgcn_mfma_f32_16x16x32_bf16(A[tk], B, c, 0, 0, 0);
            }
            int j = tj * 16 + row16;
            float bias = pb[j];
            #pragma unroll
            for (int m = 0; m < 4; ++m) {
                int n = nbase + kq * 4 + m;
                h_bf[(size_t)n * 128 + j] = (unsigned short)f2bf(c[m] + bias);
            }
        }
    }
}

// FUSED count + proj (uncapped, round-11/13 proven ~145us).
__global__ __launch_bounds__(256) void count_proj_kernel(
    const int* __restrict__ e0, const int* __restrict__ e1, const int* __restrict__ e2,
    int* __restrict__ cnt, int* __restrict__ rank,
    const float* __restrict__ x, const short* __restrict__ pwB,
    const float* __restrict__ pb, unsigned short* __restrict__ h_bf)
{
    int b = blockIdx.x;
    if (b < CNT_BLKS) {
        int r = b / 3907, eb = b % 3907;
        const int* ei = (r == 0) ? e0 : (r == 1) ? e1 : e2;
        int e = eb * 256 + threadIdx.x;
        if (e < E_EDGES) {
            int k = atomicAdd(&cnt[r * N_NODES + ei[E_EDGES + e]], 1);
            rank[(size_t)r * E_EDGES + e] = k;
        }
    } else {
        proj_body(b - CNT_BLKS, x, pwB, pb, h_bf);
    }
}

// --------------------------- scans ------------------------------------
__global__ __launch_bounds__(256) void bsum_kernel(
    const int* __restrict__ cnt, int* __restrict__ bsums)
{
    __shared__ int sh[256];
    int r = blockIdx.y, b = blockIdx.x, t = threadIdx.x;
    int i = b * 256 + t;
    sh[t] = (i < N_NODES) ? cnt[r * N_NODES + i] : 0;
    __syncthreads();
    for (int d = 128; d > 0; d >>= 1) {
        if (t < d) sh[t] += sh[t + d];
        __syncthreads();
    }
    if (t == 0) bsums[r * NBLK + b] = sh[0];
}

__global__ __launch_bounds__(512) void bscan_kernel(
    const int* __restrict__ bsums, int* __restrict__ bpre)
{
    __shared__ int sh[512];
    int r = blockIdx.x, t = threadIdx.x;
    sh[t] = (t < NBLK) ? bsums[r * NBLK + t] : 0;
    __syncthreads();
    for (int d = 1; d < 512; d <<= 1) {
        int v = (t >= d) ? sh[t - d] : 0;
        __syncthreads();
        sh[t] += v;
        __syncthreads();
    }
    if (t < NBLK) bpre[r * NBLK + t] = (t > 0) ? sh[t - 1] : 0;
}

__global__ __launch_bounds__(256) void offwrite_kernel(
    const int* __restrict__ cnt, const int* __restrict__ bpre,
    int* __restrict__ off)
{
    __shared__ int sh[256];
    int r = blockIdx.y, b = blockIdx.x, t = threadIdx.x;
    int i = b * 256 + t;
    int c = (i < N_NODES) ? cnt[r * N_NODES + i] : 0;
    sh[t] = c;
    __syncthreads();
    for (int d = 1; d < 256; d <<= 1) {
        int v = (t >= d) ? sh[t - d] : 0;
        __syncthreads();
        sh[t] += v;
        __syncthreads();
    }
    if (i < N_NODES)
        off[r * N_NODES + i] = r * E_EDGES + bpre[r * NBLK + b] + (sh[t] - c);
}

// --------------------------- a / fill bodies -------------------------------
__device__ __forceinline__ void a_body(
    int bx, const unsigned short* __restrict__ h_bf,
    const float* __restrict__ att_src, const float* __restrict__ att_dst,
    float* __restrict__ a_src, float* __restrict__ a_dst)
{
    int idx = bx * 256 + threadIdx.x;
    if (idx >= N_NODES * 8) return;
    int n = idx >> 3, hd = idx & 7;
    float hv[16];
    const unsigned short* ph = h_bf + (size_t)n * 128 + hd * 16;
    #pragma unroll
    for (int d = 0; d < 16; ++d) hv[d] = bf2f(ph[d]);
    #pragma unroll
    for (int r = 0; r < 3; ++r) {
        float vs = 0.f, vd = 0.f;
        #pragma unroll
        for (int d = 0; d < 16; ++d) {
            vs += hv[d] * att_src[(r * 8 + hd) * 16 + d];
            vd += hv[d] * att_dst[(r * 8 + hd) * 16 + d];
        }
        a_src[((size_t)r * N_NODES + n) * 8 + hd] = vs;
        a_dst[((size_t)r * N_NODES + n) * 8 + hd] = vd;
    }
}

__device__ __forceinline__ void fill_body(
    int r, int eb,
    const int* __restrict__ e0, const int* __restrict__ e1, const int* __restrict__ e2,
    const int* __restrict__ off, const int* __restrict__ rank,
    int* __restrict__ csr_rows)
{
    const int* ei = (r == 0) ? e0 : (r == 1) ? e1 : e2;
    int e = eb * 256 + threadIdx.x;
    if (e >= E_EDGES) return;
    int col = ei[E_EDGES + e];
    int pos = off[r * N_NODES + col] + rank[(size_t)r * E_EDGES + e];
    csr_rows[pos] = ei[e];
}

// FUSED a + fill(r=0). Both <=48 VGPR.
__global__ __launch_bounds__(256) void a_fill_kernel(
    const unsigned short* __restrict__ h_bf, const float* __restrict__ att_src,
    const float* __restrict__ att_dst, float* __restrict__ a_src,
    float* __restrict__ a_dst,
    const int* __restrict__ e0, const int* __restrict__ e1, const int* __restrict__ e2,
    const int* __restrict__ off, const int* __restrict__ rank,
    int* __restrict__ csr_rows)
{
    int b = blockIdx.x;
    if (b < A_BLKS) {
        a_body(b, h_bf, att_src, att_dst, a_src, a_dst);
    } else {
        int bb = b - A_BLKS;
        fill_body(bb / FILL_BLKS, bb % FILL_BLKS, e0, e1, e2, off, rank, csr_rows);
    }
}

// ---------------------------------------------------------------------------
// FUSED pull + semantic body. One block = 32 nodes.
// Phase 1 (pull): 8 half-wave units x 4 node streams, 2-edge unroll (the
//   proven round-9 shape). Out rows go to LDS bf16, row stride 272B
//   (68 u32) -> 2-way bank aliasing (free, G4) instead of 256B (16-way).
// Phase 2 (sem): wave w handles batch (w&1) [16 nodes], tj range (w>>1)*4..+4.
//   A-frags read straight from LDS (same within-row layout as the old global
//   outs: byte (row)*stride + tk*64 + kq*16). lin-proj on waves 0,1.
//   Partials -> sh[2][128] -> coalesced redpart[r][bx][128]. NO atomics,
//   NO global outs buffer (kills 150 MB of L2/L3 round-trip).
// ---------------------------------------------------------------------------
__device__ __forceinline__ void pullsem_body(
    int bx, int r,
    const unsigned short* __restrict__ h_bf, const float* __restrict__ a_src,
    const float* __restrict__ a_dst, const int* __restrict__ cnt,
    const int* __restrict__ off, const int* __restrict__ csr_rows,
    const short* __restrict__ kwB, const short* __restrict__ linB,
    const float* __restrict__ kb,
    float* __restrict__ proj_out, float* __restrict__ redpart,
    unsigned int* lds_out, float (*sh)[128])
{
    int tid = threadIdx.x;
    int wave = tid >> 6, lane = tid & 63;
    int half = lane >> 5, hl = lane & 31;
    int hd = hl >> 2;
    const size_t rbase = (size_t)r * N_NODES;
    const int CSR_LAST = R_REL * E_EDGES - 1;

    int unit = wave * 2 + half;            // 0..7
    int nb = (bx * 8 + unit) * 4;

    // ---- phase 1: pull ----
    int deg4[4], dm1[4], st4[4];
    float adv[4];
    int kmax = 0;
    #pragma unroll
    for (int i = 0; i < 4; ++i) {
        size_t rn = rbase + (nb + i);
        deg4[i] = cnt[rn];
        st4[i]  = off[rn];
        dm1[i]  = max(deg4[i] - 1, 0);
        adv[i]  = a_dst[rn * 8 + hd];
        kmax = max(kmax, deg4[i]);
    }
    float acc[4][4] = {};
    float den[4] = {0.f, 0.f, 0.f, 0.f};

    for (int k = 0; k < kmax; k += 2) {
        int rowA[4], rowB[4];
        #pragma unroll
        for (int i = 0; i < 4; ++i) {
            int kA = min(k, dm1[i]), kB = min(k + 1, dm1[i]);
            rowA[i] = csr_rows[min(st4[i] + kA, CSR_LAST)];
            rowB[i] = csr_rows[min(st4[i] + kB, CSR_LAST)];
        }
        float aA[4], aB[4];
        u32x2 hA[4], hB[4];
        #pragma unroll
        for (int i = 0; i < 4; ++i) {
            aA[i] = a_src[(rbase + rowA[i]) * 8 + hd];
            aB[i] = a_src[(rbase + rowB[i]) * 8 + hd];
            hA[i] = *(const u32x2*)(h_bf + (size_t)rowA[i] * 128 + 4 * hl);
            hB[i] = *(const u32x2*)(h_bf + (size_t)rowB[i] * 128 + 4 * hl);
        }
        #pragma unroll
        for (int i = 0; i < 4; ++i) {
            float eA = __expf(lrelu(aA[i] + adv[i]));
            float eB = __expf(lrelu(aB[i] + adv[i]));
            eA = (k     < deg4[i]) ? eA : 0.f;
            eB = (k + 1 < deg4[i]) ? eB : 0.f;
            acc[i][0] += eA * bf_lo(hA[i][0]);
            acc[i][1] += eA * bf_hi(hA[i][0]);
            acc[i][2] += eA * bf_lo(hA[i][1]);
            acc[i][3] += eA * bf_hi(hA[i][1]);
            den[i]    += eA;
            acc[i][0] += eB * bf_lo(hB[i][0]);
            acc[i][1] += eB * bf_hi(hB[i][0]);
            acc[i][2] += eB * bf_lo(hB[i][1]);
            acc[i][3] += eB * bf_hi(hB[i][1]);
            den[i]    += eB;
        }
    }
    #pragma unroll
    for (int i = 0; i < 4; ++i) {
        float inv = 1.f / (den[i] + 1e-16f);
        float o0 = fmaxf(acc[i][0] * inv, 0.f);
        float o1 = fmaxf(acc[i][1] * inv, 0.f);
        float o2 = fmaxf(acc[i][2] * inv, 0.f);
        float o3 = fmaxf(acc[i][3] * inv, 0.f);
        u32x2 p;
        p[0] = (unsigned)(unsigned short)f2bf(o0) | ((unsigned)(unsigned short)f2bf(o1) << 16);
        p[1] = (unsigned)(unsigned short)f2bf(o2) | ((unsigned)(unsigned short)f2bf(o3) << 16);
        int rl = unit * 4 + i;                       // local row 0..31
        *(u32x2*)&lds_out[rl * 68 + 2 * hl] = p;     // 272B row stride
    }
    __syncthreads();

    // ---- phase 2: semantic + lin projection ----
    int batch = wave & 1;
    int tjlo = (wave >> 1) * 4;
    int row16 = lane & 15, kq = lane >> 4;
    bf16x8 A[4];
    const char* abase = (const char*)lds_out + (batch * 16 + row16) * 272 + kq * 16;
    #pragma unroll
    for (int tk = 0; tk < 4; ++tk)
        A[tk] = *(const bf16x8*)(abase + tk * 64);

    #pragma unroll
    for (int t = 0; t < 4; ++t) {
        int tj = tjlo + t;
        f32x4 c = {0.f, 0.f, 0.f, 0.f};
        #pragma unroll
        for (int tk = 0; tk < 4; ++tk) {
            bf16x8 B = *(const bf16x8*)(kwB + ((size_t)(tj * 4 + tk) * 64 + lane) * 8);
            c = __builtin_amdgcn_mfma_f32_16x16x32_bf16(A[tk], B, c, 0, 0, 0);
        }
        float kbv = kb[tj * 16 + row16];
        float ts = 0.f;
        #pragma unroll
        for (int m = 0; m < 4; ++m) {
            float s = c[m] + kbv;
            float ex = __expf(2.f * s);
            ts += 1.f - 2.f / (ex + 1.f);
        }
        ts += __shfl_xor(ts, 16);
        ts += __shfl_xor(ts, 32);
        if (lane < 16) sh[batch][tj * 16 + lane] = ts;
    }
    if (wave < 2) {     // lin projection: wave 0 -> batch 0, wave 1 -> batch 1
        f32x4 c = {0.f, 0.f, 0.f, 0.f};
        #pragma unroll
        for (int tk = 0; tk < 4; ++tk) {
            bf16x8 B = *(const bf16x8*)(linB + ((size_t)tk * 64 + lane) * 8);
            c = __builtin_amdgcn_mfma_f32_16x16x32_bf16(A[tk], B, c, 0, 0, 0);
        }
        if (row16 < 4) {
            #pragma unroll
            for (int m = 0; m < 4; ++m) {
                int n = bx * 32 + batch * 16 + kq * 4 + m;
                proj_out[(rbase + n) * 4 + row16] = c[m];
            }
        }
    }
    __syncthreads();
    int t = threadIdx.x;
    if (t < 128)
        redpart[((size_t)r * REDN + bx) * 128 + t] = sh[0][t] + sh[1][t];
}

__global__ __launch_bounds__(256) void pullsem_kernel(
    const unsigned short* __restrict__ h_bf, const float* __restrict__ a_src,
    const float* __restrict__ a_dst, const int* __restrict__ cnt,
    const int* __restrict__ off, const int* __restrict__ csr_rows,
    const short* __restrict__ kwB, const short* __restrict__ linB,
    const float* __restrict__ kb,
    float* __restrict__ proj_out, float* __restrict__ redpart, int r)
{
    __shared__ __align__(16) unsigned int lds_out[32 * 68];
    __shared__ float sh[2][128];
    pullsem_body(blockIdx.x, r, h_bf, a_src, a_dst, cnt, off, csr_rows,
                 kwB, linB, kb, proj_out, redpart, lds_out, sh);
}

// FUSED pullsem(r=0) + fill(r=1,2) riders.
__global__ __launch_bounds__(256) void ps0_fill12_kernel(
    const unsigned short* __restrict__ h_bf, const float* __restrict__ a_src,
    const float* __restrict__ a_dst, const int* __restrict__ cnt,
    const int* __restrict__ off, const int* __restrict__ csr_rows,
    const short* __restrict__ kwB, const short* __restrict__ linB,
    const float* __restrict__ kb,
    float* __restrict__ proj_out, float* __restrict__ redpart,
    const int* __restrict__ e0, const int* __restrict__ e1, const int* __restrict__ e2,
    const int* __restrict__ rank, int* __restrict__ csr_w)
{
    __shared__ __align__(16) unsigned int lds_out[32 * 68];
    __shared__ float sh[2][128];
    int b = blockIdx.x;
    if (b < PS_BLKS) {
        pullsem_body(b, 0, h_bf, a_src, a_dst, cnt, off, csr_rows,
                     kwB, linB, kb, proj_out, redpart, lds_out, sh);
    } else {
        int bb = b - PS_BLKS;
        fill_body(1 + bb / FILL_BLKS, bb % FILL_BLKS, e0, e1, e2, off, rank, csr_w);
    }
}

// ---------------------------------------------------------------------------
__global__ __launch_bounds__(256) void redreduce_kernel(
    const float* __restrict__ redpart, float* __restrict__ red)
{
    __shared__ float sh[2][128];
    int r = blockIdx.x;
    int t = threadIdx.x;
    int j = t & 127, half = t >> 7;
    float s = 0.f;
    for (int b = half; b < REDN; b += 2)
        s += redpart[((size_t)r * REDN + b) * 128 + j];
    sh[half][j] = s;
    __syncthreads();
    if (t < 128) red[r * 128 + t] = sh[0][t] + sh[1][t];
}

__global__ void attn_kernel(const float* __restrict__ red, const float* __restrict__ q,
                            float* __restrict__ attn)
{
    int lane = threadIdx.x;
    float p[3];
    #pragma unroll
    for (int r = 0; r < 3; ++r) {
        float v = q[lane] * red[r * 128 + lane] + q[lane + 64] * red[r * 128 + lane + 64];
        for (int sft = 32; sft; sft >>= 1) v += __shfl_down(v, sft);
        p[r] = v;
    }
    if (lane == 0) {
        float s0 = p[0] / (float)N_NODES;
        float s1 = p[1] / (float)N_NODES;
        float s2 = p[2] / (float)N_NODES;
        float m = fmaxf(s0, fmaxf(s1, s2));
        float e0 = __expf(s0 - m), e1 = __expf(s1 - m), e2 = __expf(s2 - m);
        float inv = 1.f / (e0 + e1 + e2);
        attn[0] = e0 * inv; attn[1] = e1 * inv; attn[2] = e2 * inv;
    }
}

__global__ __launch_bounds__(256) void final_kernel(
    const float* __restrict__ proj_out, const float* __restrict__ attn,
    const float* __restrict__ lb, float* __restrict__ out)
{
    int i = blockIdx.x * 256 + threadIdx.x;
    if (i >= N_NODES * 4) return;
    int o = i & 3;
    out[i] = attn[0] * proj_out[i]
           + attn[1] * proj_out[(size_t)N_NODES * 4 + i]
           + attn[2] * proj_out[(size_t)2 * N_NODES * 4 + i]
           + lb[o];
}

extern "C" void kernel_launch(void* const* d_in, const int* in_sizes, int n_in,
                              void* d_out, int out_size, void* d_ws, size_t ws_size,
                              hipStream_t stream)
{
    const float* x       = (const float*)d_in[0];
    const int*   e0      = (const int*)d_in[1];
    const int*   e1      = (const int*)d_in[2];
    const int*   e2      = (const int*)d_in[3];
    const float* pw      = (const float*)d_in[4];
    const float* pb      = (const float*)d_in[5];
    const float* att_src = (const float*)d_in[6];
    const float* att_dst = (const float*)d_in[7];
    const float* kw      = (const float*)d_in[8];
    const float* kb      = (const float*)d_in[9];
    const float* q       = (const float*)d_in[10];
    const float* lw      = (const float*)d_in[11];
    const float* lb      = (const float*)d_in[12];
    float* out = (float*)d_out;

    // Layout (float units). Global outs buffer ELIMINATED; its old slot now
    // holds rank (3M ints) + redpart (1.2M floats). Total ~89.7 MB, single path.
    float* ws = (float*)d_ws;
    unsigned short* h_bf    = (unsigned short*)ws;     // 12.8M ushort
    float*          a_src   = ws + 6400000;            // 2.4M
    float*          a_dst   = ws + 8800000;            // 2.4M
    int*            rank    = (int*)(ws + 11200000);   // 3.0M ints
    float*          redpart = ws + 14200000;           // 3*3125*128 = 1.2M
    float*          proj_out= ws + 17600000;           // 1.2M
    float*          red     = ws + 18800000;           // 384
    float*          attn    = ws + 18800384;           // 4
    short*          kwB     = (short*)(ws + 18800388); // 16384 short
    short*          pwB     = (short*)(ws + 18808580); // 16384 short
    short*          linB    = (short*)(ws + 18816772); // 2048 short
    int*            cnt     = (int*)(ws + 18817796);   // 300,000
    int*            off     = (int*)(ws + 19117796);   // 300,000
    int*            csr_rows= (int*)(ws + 19417796);   // 3,000,000
    int*            bsums   = (int*)(ws + 22417796);   // 1,173
    int*            bpre    = (int*)(ws + 22418969);   // 1,173

    hipMemsetAsync(cnt, 0, 300000 * sizeof(int), stream);

    prep_kernel<<<dim3(136), dim3(256), 0, stream>>>(kw, pw, lw, kwB, pwB, linB);
    count_proj_kernel<<<dim3(CNT_BLKS + PROJ_BLKS), dim3(256), 0, stream>>>(
        e0, e1, e2, cnt, rank, x, pwB, pb, h_bf);
    bsum_kernel<<<dim3(NBLK, 3), dim3(256), 0, stream>>>(cnt, bsums);
    bscan_kernel<<<dim3(3), dim3(512), 0, stream>>>(bsums, bpre);
    offwrite_kernel<<<dim3(NBLK, 3), dim3(256), 0, stream>>>(cnt, bpre, off);

    a_fill_kernel<<<dim3(A_BLKS + FILL_BLKS), dim3(256), 0, stream>>>(
        h_bf, att_src, att_dst, a_src, a_dst, e0, e1, e2, off, rank, csr_rows);
    ps0_fill12_kernel<<<dim3(PS_BLKS + 2 * FILL_BLKS), dim3(256), 0, stream>>>(
        h_bf, a_src, a_dst, cnt, off, csr_rows, kwB, linB, kb,
        proj_out, redpart, e0, e1, e2, rank, csr_rows);
    pullsem_kernel<<<dim3(PS_BLKS), dim3(256), 0, stream>>>(
        h_bf, a_src, a_dst, cnt, off, csr_rows, kwB, linB, kb,
        proj_out, redpart, 1);
    pullsem_kernel<<<dim3(PS_BLKS), dim3(256), 0, stream>>>(
        h_bf, a_src, a_dst, cnt, off, csr_rows, kwB, linB, kb,
        proj_out, redpart, 2);

    redreduce_kernel<<<dim3(3), dim3(256), 0, stream>>>(redpart, red);
    attn_kernel<<<dim3(1), dim3(64), 0, stream>>>(red, q, attn);
    final_kernel<<<dim3(1563), dim3(256), 0, stream>>>(proj_out, attn, lb, out);
}

// Round 15
// 428.427 us; speedup vs baseline: 1.8019x; 1.8019x over previous
//
#include <hip/hip_runtime.h>

#define N_NODES 100000
#define E_EDGES 1000000
#define R_REL   3
#define NBATCH  6250          // N_NODES / 16
#define NBLK    391           // ceil(N_NODES / 256)
#define CNT_BLKS  11721       // 3907 * 3
#define PROJ_BLKS 391
#define A_BLKS    3125        // 800000 / 256
#define FILL_BLKS 3907
#define PS_BLKS   3125        // pull+sem blocks (32 nodes each)
#define REDN      3125        // redpart partials per relation
#define RED_CH    25          // level-1 chunks (3125 = 25 * 125)

using bf16x8 = __attribute__((ext_vector_type(8))) short;
using f32x4  = __attribute__((ext_vector_type(4))) float;
using u32x2  = __attribute__((ext_vector_type(2))) unsigned int;

__device__ __forceinline__ float lrelu(float x) { return fmaxf(x, 0.2f * x); }

__device__ __forceinline__ short f2bf(float f) {   // RNE f32->bf16
    unsigned u = __builtin_bit_cast(unsigned, f);
    u += 0x7FFFu + ((u >> 16) & 1u);
    return (short)(u >> 16);
}
__device__ __forceinline__ float bf_lo(unsigned u) {
    return __builtin_bit_cast(float, u << 16);
}
__device__ __forceinline__ float bf_hi(unsigned u) {
    return __builtin_bit_cast(float, u & 0xFFFF0000u);
}
__device__ __forceinline__ float bf2f(unsigned short u) {
    return __builtin_bit_cast(float, ((unsigned)u) << 16);
}

// ---------------------------------------------------------------------------
// Bake bf16 B-fragments for 16x16x32 MFMA (kw, pw full 128x128; lin 4x128).
// ---------------------------------------------------------------------------
__global__ __launch_bounds__(256) void prep_kernel(
    const float* __restrict__ kw, const float* __restrict__ pw,
    const float* __restrict__ lw,
    short* __restrict__ kwB, short* __restrict__ pwB, short* __restrict__ linB)
{
    int idx = blockIdx.x * 256 + threadIdx.x;
    int which, rem;
    if      (idx < 16384) { which = 0; rem = idx; }
    else if (idx < 32768) { which = 1; rem = idx - 16384; }
    else if (idx < 34816) { which = 2; rem = idx - 32768; }
    else return;
    int e = rem & 7, lane = (rem >> 3) & 63, t = rem >> 9;
    int tj = (which == 2) ? 0 : (t >> 2);
    int tk = (which == 2) ? t : (t & 3);
    int j = tj * 16 + (lane & 15);
    int k = tk * 32 + (lane >> 4) * 8 + e;
    const float* src = (which == 0) ? kw : (which == 1) ? pw : lw;
    float v = (which == 2 && j >= 4) ? 0.f : src[j * 128 + k];
    short* dst = (which == 0) ? kwB : (which == 1) ? pwB : linB;
    dst[rem] = f2bf(v);
}

// ---------------------------------------------------------------------------
// proj body (MFMA, full unroll — proven).
// ---------------------------------------------------------------------------
__device__ __forceinline__ void proj_body(
    int bx, const float* __restrict__ x, const short* __restrict__ pwB,
    const float* __restrict__ pb, unsigned short* __restrict__ h_bf)
{
    int wave = threadIdx.x >> 6, lane = threadIdx.x & 63;
    int row16 = lane & 15, kq = lane >> 4;
    for (int b = bx * 4 + wave; b < NBATCH; b += PROJ_BLKS * 4) {
        int nbase = b * 16;
        bf16x8 A[4];
        #pragma unroll
        for (int tk = 0; tk < 4; ++tk) {
            const float* px = x + (size_t)(nbase + row16) * 128 + tk * 32 + kq * 8;
            f32x4 lo = *(const f32x4*)px;
            f32x4 hi = *(const f32x4*)(px + 4);
            bf16x8 a;
            a[0] = f2bf(lo[0]); a[1] = f2bf(lo[1]); a[2] = f2bf(lo[2]); a[3] = f2bf(lo[3]);
            a[4] = f2bf(hi[0]); a[5] = f2bf(hi[1]); a[6] = f2bf(hi[2]); a[7] = f2bf(hi[3]);
            A[tk] = a;
        }
        #pragma unroll
        for (int tj = 0; tj < 8; ++tj) {
            f32x4 c = {0.f, 0.f, 0.f, 0.f};
            #pragma unroll
            for (int tk = 0; tk < 4; ++tk) {
                bf16x8 B = *(const bf16x8*)(pwB + ((size_t)(tj * 4 + tk) * 64 + lane) * 8);
                c = __builtin_amdgcn_mfma_f32_16x16x32_bf16(A[tk], B, c, 0, 0, 0);
            }
            int j = tj * 16 + row16;
            float bias = pb[j];
            #pragma unroll
            for (int m = 0; m < 4; ++m) {
                int n = nbase + kq * 4 + m;
                h_bf[(size_t)n * 128 + j] = (unsigned short)f2bf(c[m] + bias);
            }
        }
    }
}

// FUSED count + proj (uncapped, proven ~145us).
__global__ __launch_bounds__(256) void count_proj_kernel(
    const int* __restrict__ e0, const int* __restrict__ e1, const int* __restrict__ e2,
    int* __restrict__ cnt, int* __restrict__ rank,
    const float* __restrict__ x, const short* __restrict__ pwB,
    const float* __restrict__ pb, unsigned short* __restrict__ h_bf)
{
    int b = blockIdx.x;
    if (b < CNT_BLKS) {
        int r = b / 3907, eb = b % 3907;
        const int* ei = (r == 0) ? e0 : (r == 1) ? e1 : e2;
        int e = eb * 256 + threadIdx.x;
        if (e < E_EDGES) {
            int k = atomicAdd(&cnt[r * N_NODES + ei[E_EDGES + e]], 1);
            rank[(size_t)r * E_EDGES + e] = k;
        }
    } else {
        proj_body(b - CNT_BLKS, x, pwB, pb, h_bf);
    }
}

// --------------------------- scans ------------------------------------
__global__ __launch_bounds__(256) void bsum_kernel(
    const int* __restrict__ cnt, int* __restrict__ bsums)
{
    __shared__ int sh[256];
    int r = blockIdx.y, b = blockIdx.x, t = threadIdx.x;
    int i = b * 256 + t;
    sh[t] = (i < N_NODES) ? cnt[r * N_NODES + i] : 0;
    __syncthreads();
    for (int d = 128; d > 0; d >>= 1) {
        if (t < d) sh[t] += sh[t + d];
        __syncthreads();
    }
    if (t == 0) bsums[r * NBLK + b] = sh[0];
}

__global__ __launch_bounds__(512) void bscan_kernel(
    const int* __restrict__ bsums, int* __restrict__ bpre)
{
    __shared__ int sh[512];
    int r = blockIdx.x, t = threadIdx.x;
    sh[t] = (t < NBLK) ? bsums[r * NBLK + t] : 0;
    __syncthreads();
    for (int d = 1; d < 512; d <<= 1) {
        int v = (t >= d) ? sh[t - d] : 0;
        __syncthreads();
        sh[t] += v;
        __syncthreads();
    }
    if (t < NBLK) bpre[r * NBLK + t] = (t > 0) ? sh[t - 1] : 0;
}

__global__ __launch_bounds__(256) void offwrite_kernel(
    const int* __restrict__ cnt, const int* __restrict__ bpre,
    int* __restrict__ off)
{
    __shared__ int sh[256];
    int r = blockIdx.y, b = blockIdx.x, t = threadIdx.x;
    int i = b * 256 + t;
    int c = (i < N_NODES) ? cnt[r * N_NODES + i] : 0;
    sh[t] = c;
    __syncthreads();
    for (int d = 1; d < 256; d <<= 1) {
        int v = (t >= d) ? sh[t - d] : 0;
        __syncthreads();
        sh[t] += v;
        __syncthreads();
    }
    if (i < N_NODES)
        off[r * N_NODES + i] = r * E_EDGES + bpre[r * NBLK + b] + (sh[t] - c);
}

// --------------------------- a / fill bodies -------------------------------
__device__ __forceinline__ void a_body(
    int bx, const unsigned short* __restrict__ h_bf,
    const float* __restrict__ att_src, const float* __restrict__ att_dst,
    float* __restrict__ a_src, float* __restrict__ a_dst)
{
    int idx = bx * 256 + threadIdx.x;
    if (idx >= N_NODES * 8) return;
    int n = idx >> 3, hd = idx & 7;
    float hv[16];
    const unsigned short* ph = h_bf + (size_t)n * 128 + hd * 16;
    #pragma unroll
    for (int d = 0; d < 16; ++d) hv[d] = bf2f(ph[d]);
    #pragma unroll
    for (int r = 0; r < 3; ++r) {
        float vs = 0.f, vd = 0.f;
        #pragma unroll
        for (int d = 0; d < 16; ++d) {
            vs += hv[d] * att_src[(r * 8 + hd) * 16 + d];
            vd += hv[d] * att_dst[(r * 8 + hd) * 16 + d];
        }
        a_src[((size_t)r * N_NODES + n) * 8 + hd] = vs;
        a_dst[((size_t)r * N_NODES + n) * 8 + hd] = vd;
    }
}

__device__ __forceinline__ void fill_body(
    int r, int eb,
    const int* __restrict__ e0, const int* __restrict__ e1, const int* __restrict__ e2,
    const int* __restrict__ off, const int* __restrict__ rank,
    int* __restrict__ csr_rows)
{
    const int* ei = (r == 0) ? e0 : (r == 1) ? e1 : e2;
    int e = eb * 256 + threadIdx.x;
    if (e >= E_EDGES) return;
    int col = ei[E_EDGES + e];
    int pos = off[r * N_NODES + col] + rank[(size_t)r * E_EDGES + e];
    csr_rows[pos] = ei[e];
}

// FUSED a + fill(r=0). Both <=48 VGPR.
__global__ __launch_bounds__(256) void a_fill_kernel(
    const unsigned short* __restrict__ h_bf, const float* __restrict__ att_src,
    const float* __restrict__ att_dst, float* __restrict__ a_src,
    float* __restrict__ a_dst,
    const int* __restrict__ e0, const int* __restrict__ e1, const int* __restrict__ e2,
    const int* __restrict__ off, const int* __restrict__ rank,
    int* __restrict__ csr_rows)
{
    int b = blockIdx.x;
    if (b < A_BLKS) {
        a_body(b, h_bf, att_src, att_dst, a_src, a_dst);
    } else {
        int bb = b - A_BLKS;
        fill_body(bb / FILL_BLKS, bb % FILL_BLKS, e0, e1, e2, off, rank, csr_rows);
    }
}

// ---------------------------------------------------------------------------
// FUSED pull + semantic body (round-14 proven). One block = 32 nodes.
// ---------------------------------------------------------------------------
__device__ __forceinline__ void pullsem_body(
    int bx, int r,
    const unsigned short* __restrict__ h_bf, const float* __restrict__ a_src,
    const float* __restrict__ a_dst, const int* __restrict__ cnt,
    const int* __restrict__ off, const int* __restrict__ csr_rows,
    const short* __restrict__ kwB, const short* __restrict__ linB,
    const float* __restrict__ kb,
    float* __restrict__ proj_out, float* __restrict__ redpart,
    unsigned int* lds_out, float (*sh)[128])
{
    int tid = threadIdx.x;
    int wave = tid >> 6, lane = tid & 63;
    int half = lane >> 5, hl = lane & 31;
    int hd = hl >> 2;
    const size_t rbase = (size_t)r * N_NODES;
    const int CSR_LAST = R_REL * E_EDGES - 1;

    int unit = wave * 2 + half;            // 0..7
    int nb = (bx * 8 + unit) * 4;

    // ---- phase 1: pull ----
    int deg4[4], dm1[4], st4[4];
    float adv[4];
    int kmax = 0;
    #pragma unroll
    for (int i = 0; i < 4; ++i) {
        size_t rn = rbase + (nb + i);
        deg4[i] = cnt[rn];
        st4[i]  = off[rn];
        dm1[i]  = max(deg4[i] - 1, 0);
        adv[i]  = a_dst[rn * 8 + hd];
        kmax = max(kmax, deg4[i]);
    }
    float acc[4][4] = {};
    float den[4] = {0.f, 0.f, 0.f, 0.f};

    for (int k = 0; k < kmax; k += 2) {
        int rowA[4], rowB[4];
        #pragma unroll
        for (int i = 0; i < 4; ++i) {
            int kA = min(k, dm1[i]), kB = min(k + 1, dm1[i]);
            rowA[i] = csr_rows[min(st4[i] + kA, CSR_LAST)];
            rowB[i] = csr_rows[min(st4[i] + kB, CSR_LAST)];
        }
        float aA[4], aB[4];
        u32x2 hA[4], hB[4];
        #pragma unroll
        for (int i = 0; i < 4; ++i) {
            aA[i] = a_src[(rbase + rowA[i]) * 8 + hd];
            aB[i] = a_src[(rbase + rowB[i]) * 8 + hd];
            hA[i] = *(const u32x2*)(h_bf + (size_t)rowA[i] * 128 + 4 * hl);
            hB[i] = *(const u32x2*)(h_bf + (size_t)rowB[i] * 128 + 4 * hl);
        }
        #pragma unroll
        for (int i = 0; i < 4; ++i) {
            float eA = __expf(lrelu(aA[i] + adv[i]));
            float eB = __expf(lrelu(aB[i] + adv[i]));
            eA = (k     < deg4[i]) ? eA : 0.f;
            eB = (k + 1 < deg4[i]) ? eB : 0.f;
            acc[i][0] += eA * bf_lo(hA[i][0]);
            acc[i][1] += eA * bf_hi(hA[i][0]);
            acc[i][2] += eA * bf_lo(hA[i][1]);
            acc[i][3] += eA * bf_hi(hA[i][1]);
            den[i]    += eA;
            acc[i][0] += eB * bf_lo(hB[i][0]);
            acc[i][1] += eB * bf_hi(hB[i][0]);
            acc[i][2] += eB * bf_lo(hB[i][1]);
            acc[i][3] += eB * bf_hi(hB[i][1]);
            den[i]    += eB;
        }
    }
    #pragma unroll
    for (int i = 0; i < 4; ++i) {
        float inv = 1.f / (den[i] + 1e-16f);
        float o0 = fmaxf(acc[i][0] * inv, 0.f);
        float o1 = fmaxf(acc[i][1] * inv, 0.f);
        float o2 = fmaxf(acc[i][2] * inv, 0.f);
        float o3 = fmaxf(acc[i][3] * inv, 0.f);
        u32x2 p;
        p[0] = (unsigned)(unsigned short)f2bf(o0) | ((unsigned)(unsigned short)f2bf(o1) << 16);
        p[1] = (unsigned)(unsigned short)f2bf(o2) | ((unsigned)(unsigned short)f2bf(o3) << 16);
        int rl = unit * 4 + i;                       // local row 0..31
        *(u32x2*)&lds_out[rl * 68 + 2 * hl] = p;     // 272B row stride
    }
    __syncthreads();

    // ---- phase 2: semantic + lin projection ----
    int batch = wave & 1;
    int tjlo = (wave >> 1) * 4;
    int row16 = lane & 15, kq = lane >> 4;
    bf16x8 A[4];
    const char* abase = (const char*)lds_out + (batch * 16 + row16) * 272 + kq * 16;
    #pragma unroll
    for (int tk = 0; tk < 4; ++tk)
        A[tk] = *(const bf16x8*)(abase + tk * 64);

    #pragma unroll
    for (int t = 0; t < 4; ++t) {
        int tj = tjlo + t;
        f32x4 c = {0.f, 0.f, 0.f, 0.f};
        #pragma unroll
        for (int tk = 0; tk < 4; ++tk) {
            bf16x8 B = *(const bf16x8*)(kwB + ((size_t)(tj * 4 + tk) * 64 + lane) * 8);
            c = __builtin_amdgcn_mfma_f32_16x16x32_bf16(A[tk], B, c, 0, 0, 0);
        }
        float kbv = kb[tj * 16 + row16];
        float ts = 0.f;
        #pragma unroll
        for (int m = 0; m < 4; ++m) {
            float s = c[m] + kbv;
            float ex = __expf(2.f * s);
            ts += 1.f - 2.f / (ex + 1.f);
        }
        ts += __shfl_xor(ts, 16);
        ts += __shfl_xor(ts, 32);
        if (lane < 16) sh[batch][tj * 16 + lane] = ts;
    }
    if (wave < 2) {     // lin projection: wave 0 -> batch 0, wave 1 -> batch 1
        f32x4 c = {0.f, 0.f, 0.f, 0.f};
        #pragma unroll
        for (int tk = 0; tk < 4; ++tk) {
            bf16x8 B = *(const bf16x8*)(linB + ((size_t)tk * 64 + lane) * 8);
            c = __builtin_amdgcn_mfma_f32_16x16x32_bf16(A[tk], B, c, 0, 0, 0);
        }
        if (row16 < 4) {
            #pragma unroll
            for (int m = 0; m < 4; ++m) {
                int n = bx * 32 + batch * 16 + kq * 4 + m;
                proj_out[(rbase + n) * 4 + row16] = c[m];
            }
        }
    }
    __syncthreads();
    int t = threadIdx.x;
    if (t < 128)
        redpart[((size_t)r * REDN + bx) * 128 + t] = sh[0][t] + sh[1][t];
}

__global__ __launch_bounds__(256) void pullsem_kernel(
    const unsigned short* __restrict__ h_bf, const float* __restrict__ a_src,
    const float* __restrict__ a_dst, const int* __restrict__ cnt,
    const int* __restrict__ off, const int* __restrict__ csr_rows,
    const short* __restrict__ kwB, const short* __restrict__ linB,
    const float* __restrict__ kb,
    float* __restrict__ proj_out, float* __restrict__ redpart, int r)
{
    __shared__ __align__(16) unsigned int lds_out[32 * 68];
    __shared__ float sh[2][128];
    pullsem_body(blockIdx.x, r, h_bf, a_src, a_dst, cnt, off, csr_rows,
                 kwB, linB, kb, proj_out, redpart, lds_out, sh);
}

// FUSED pullsem(r=0) + fill(r=1,2) riders.
__global__ __launch_bounds__(256) void ps0_fill12_kernel(
    const unsigned short* __restrict__ h_bf, const float* __restrict__ a_src,
    const float* __restrict__ a_dst, const int* __restrict__ cnt,
    const int* __restrict__ off, const int* __restrict__ csr_rows,
    const short* __restrict__ kwB, const short* __restrict__ linB,
    const float* __restrict__ kb,
    float* __restrict__ proj_out, float* __restrict__ redpart,
    const int* __restrict__ e0, const int* __restrict__ e1, const int* __restrict__ e2,
    const int* __restrict__ rank, int* __restrict__ csr_w)
{
    __shared__ __align__(16) unsigned int lds_out[32 * 68];
    __shared__ float sh[2][128];
    int b = blockIdx.x;
    if (b < PS_BLKS) {
        pullsem_body(b, 0, h_bf, a_src, a_dst, cnt, off, csr_rows,
                     kwB, linB, kb, proj_out, redpart, lds_out, sh);
    } else {
        int bb = b - PS_BLKS;
        fill_body(1 + bb / FILL_BLKS, bb % FILL_BLKS, e0, e1, e2, off, rank, csr_w);
    }
}

// ---------------------------------------------------------------------------
// Two-level redreduce (round-14 lesson: 3-block serial loop over 3125
// partials was 367us at 0.14% occupancy — same mistake as round-6 scan).
// Level 1: (RED_CH, 3) blocks, each sums 125 partials -> red2[r][c][128].
// Level 2: 3 blocks, each sums RED_CH chunks -> red[r][128].
// ---------------------------------------------------------------------------
__global__ __launch_bounds__(256) void redreduce1_kernel(
    const float* __restrict__ redpart, float* __restrict__ red2)
{
    __shared__ float sh[2][128];
    int r = blockIdx.y, c = blockIdx.x;
    int t = threadIdx.x;
    int j = t & 127, half = t >> 7;
    float s = 0.f;
    int b0 = c * 125;
    for (int b = b0 + half; b < b0 + 125; b += 2)
        s += redpart[((size_t)r * REDN + b) * 128 + j];
    sh[half][j] = s;
    __syncthreads();
    if (t < 128) red2[((size_t)r * RED_CH + c) * 128 + t] = sh[0][t] + sh[1][t];
}

__global__ __launch_bounds__(256) void redreduce2_kernel(
    const float* __restrict__ red2, float* __restrict__ red)
{
    __shared__ float sh[2][128];
    int r = blockIdx.x;
    int t = threadIdx.x;
    int j = t & 127, half = t >> 7;
    float s = 0.f;
    for (int c = half; c < RED_CH; c += 2)
        s += red2[((size_t)r * RED_CH + c) * 128 + j];
    sh[half][j] = s;
    __syncthreads();
    if (t < 128) red[r * 128 + t] = sh[0][t] + sh[1][t];
}

__global__ void attn_kernel(const float* __restrict__ red, const float* __restrict__ q,
                            float* __restrict__ attn)
{
    int lane = threadIdx.x;
    float p[3];
    #pragma unroll
    for (int r = 0; r < 3; ++r) {
        float v = q[lane] * red[r * 128 + lane] + q[lane + 64] * red[r * 128 + lane + 64];
        for (int sft = 32; sft; sft >>= 1) v += __shfl_down(v, sft);
        p[r] = v;
    }
    if (lane == 0) {
        float s0 = p[0] / (float)N_NODES;
        float s1 = p[1] / (float)N_NODES;
        float s2 = p[2] / (float)N_NODES;
        float m = fmaxf(s0, fmaxf(s1, s2));
        float e0 = __expf(s0 - m), e1 = __expf(s1 - m), e2 = __expf(s2 - m);
        float inv = 1.f / (e0 + e1 + e2);
        attn[0] = e0 * inv; attn[1] = e1 * inv; attn[2] = e2 * inv;
    }
}

__global__ __launch_bounds__(256) void final_kernel(
    const float* __restrict__ proj_out, const float* __restrict__ attn,
    const float* __restrict__ lb, float* __restrict__ out)
{
    int i = blockIdx.x * 256 + threadIdx.x;
    if (i >= N_NODES * 4) return;
    int o = i & 3;
    out[i] = attn[0] * proj_out[i]
           + attn[1] * proj_out[(size_t)N_NODES * 4 + i]
           + attn[2] * proj_out[(size_t)2 * N_NODES * 4 + i]
           + lb[o];
}

extern "C" void kernel_launch(void* const* d_in, const int* in_sizes, int n_in,
                              void* d_out, int out_size, void* d_ws, size_t ws_size,
                              hipStream_t stream)
{
    const float* x       = (const float*)d_in[0];
    const int*   e0      = (const int*)d_in[1];
    const int*   e1      = (const int*)d_in[2];
    const int*   e2      = (const int*)d_in[3];
    const float* pw      = (const float*)d_in[4];
    const float* pb      = (const float*)d_in[5];
    const float* att_src = (const float*)d_in[6];
    const float* att_dst = (const float*)d_in[7];
    const float* kw      = (const float*)d_in[8];
    const float* kb      = (const float*)d_in[9];
    const float* q       = (const float*)d_in[10];
    const float* lw      = (const float*)d_in[11];
    const float* lb      = (const float*)d_in[12];
    float* out = (float*)d_out;

    // Layout (float units). ~89.8 MB, single deterministic path.
    float* ws = (float*)d_ws;
    unsigned short* h_bf    = (unsigned short*)ws;     // 12.8M ushort
    float*          a_src   = ws + 6400000;            // 2.4M
    float*          a_dst   = ws + 8800000;            // 2.4M
    int*            rank    = (int*)(ws + 11200000);   // 3.0M ints
    float*          redpart = ws + 14200000;           // 3*3125*128 = 1.2M
    float*          red2    = ws + 15400000;           // 3*25*128 = 9600
    float*          proj_out= ws + 17600000;           // 1.2M
    float*          red     = ws + 18800000;           // 384
    float*          attn    = ws + 18800384;           // 4
    short*          kwB     = (short*)(ws + 18800388); // 16384 short
    short*          pwB     = (short*)(ws + 18808580); // 16384 short
    short*          linB    = (short*)(ws + 18816772); // 2048 short
    int*            cnt     = (int*)(ws + 18817796);   // 300,000
    int*            off     = (int*)(ws + 19117796);   // 300,000
    int*            csr_rows= (int*)(ws + 19417796);   // 3,000,000
    int*            bsums   = (int*)(ws + 22417796);   // 1,173
    int*            bpre    = (int*)(ws + 22418969);   // 1,173

    hipMemsetAsync(cnt, 0, 300000 * sizeof(int), stream);

    prep_kernel<<<dim3(136), dim3(256), 0, stream>>>(kw, pw, lw, kwB, pwB, linB);
    count_proj_kernel<<<dim3(CNT_BLKS + PROJ_BLKS), dim3(256), 0, stream>>>(
        e0, e1, e2, cnt, rank, x, pwB, pb, h_bf);
    bsum_kernel<<<dim3(NBLK, 3), dim3(256), 0, stream>>>(cnt, bsums);
    bscan_kernel<<<dim3(3), dim3(512), 0, stream>>>(bsums, bpre);
    offwrite_kernel<<<dim3(NBLK, 3), dim3(256), 0, stream>>>(cnt, bpre, off);

    a_fill_kernel<<<dim3(A_BLKS + FILL_BLKS), dim3(256), 0, stream>>>(
        h_bf, att_src, att_dst, a_src, a_dst, e0, e1, e2, off, rank, csr_rows);
    ps0_fill12_kernel<<<dim3(PS_BLKS + 2 * FILL_BLKS), dim3(256), 0, stream>>>(
        h_bf, a_src, a_dst, cnt, off, csr_rows, kwB, linB, kb,
        proj_out, redpart, e0, e1, e2, rank, csr_rows);
    pullsem_kernel<<<dim3(PS_BLKS), dim3(256), 0, stream>>>(
        h_bf, a_src, a_dst, cnt, off, csr_rows, kwB, linB, kb,
        proj_out, redpart, 1);
    pullsem_kernel<<<dim3(PS_BLKS), dim3(256), 0, stream>>>(
        h_bf, a_src, a_dst, cnt, off, csr_rows, kwB, linB, kb,
        proj_out, redpart, 2);

    redreduce1_kernel<<<dim3(RED_CH, 3), dim3(256), 0, stream>>>(redpart, red2);
    redreduce2_kernel<<<dim3(3), dim3(256), 0, stream>>>(red2, red);
    attn_kernel<<<dim3(1), dim3(64), 0, stream>>>(red, q, attn);
    final_kernel<<<dim3(1563), dim3(256), 0, stream>>>(proj_out, attn, lb, out);
}